// Round 4
// baseline (81.948 us; speedup 1.0000x reference)
//
#include <hip/hip_runtime.h>

// ItemCode: PQ-coded embedding reconstruction.
//   input_ids : (256, 512) int32
//   item_codes: (1000000, 8) int32
//   centroids : (8, 256, 64) float32   (row 0 of each subspace is all-zero)
//   out       : (256, 512, 512) float32
//
// Block = (m, chunk of 512 tokens). The m-subtable (256 codes x 256 B = 64 KB)
// is staged in LDS once; the hot loop is then pure {LDS read -> NT store} with
// ONE barrier total (round-3 lesson: __syncthreads drains vmcnt incl. stores,
// so barriers inside the store stream serialize it).
// Pad tokens (id==0) route to code 0, whose centroid row is all-zero.

#define VALS_ 256
#define NTOK_ (256 * 512)
#define T_BLK 512                 // tokens per block
#define THREADS 256
#define ROWS_F4 16                // float4 per centroid row (64 floats)

typedef float f4 __attribute__((ext_vector_type(4)));

__global__ __launch_bounds__(THREADS) void ItemCode_kernel(
    const int* __restrict__ input_ids,
    const int* __restrict__ item_codes,
    const float* __restrict__ centroids,
    float* __restrict__ out)
{
    __shared__ f4  s_tab[VALS_ * ROWS_F4];   // 64 KB: this block's m-subtable
    __shared__ int s_off[T_BLK];             // 2 KB: per-token row base (code*16)

    const int bid   = blockIdx.x;
    const int m     = bid & 7;               // 8 m-blocks of a chunk run together
    const int chunk = bid >> 3;
    const int tid   = threadIdx.x;
    const int tok0  = chunk * T_BLK;

    const f4* __restrict__ cent4 =
        reinterpret_cast<const f4*>(centroids) + m * (VALS_ * ROWS_F4);

    // --- random code gather first (longest latency), table stage underneath
    const int id0 = input_ids[tok0 + tid];
    const int id1 = input_ids[tok0 + THREADS + tid];

    #pragma unroll
    for (int k = 0; k < ROWS_F4; ++k)        // 64 KB linear, L2-resident
        s_tab[k * THREADS + tid] = cent4[k * THREADS + tid];

    int c0 = min(__builtin_nontemporal_load(&item_codes[id0 * 8 + m]), VALS_ - 1);
    int c1 = min(__builtin_nontemporal_load(&item_codes[id1 * 8 + m]), VALS_ - 1);
    s_off[tid]           = (id0 ? c0 : 0) << 4;
    s_off[tid + THREADS] = (id1 ? c1 : 0) << 4;

    __syncthreads();                         // the ONLY barrier

    // --- stream: 16 lanes per token; b128 reads spread uniformly over banks
    const int t_lo = tid >> 4;               // 0..15
    const int s4   = tid & 15;
    f4* __restrict__ out4 = reinterpret_cast<f4*>(out);
    const int obase = (tok0 + t_lo) * 128 + m * 16 + s4;   // f4 index, < 2^24

    #pragma unroll 8
    for (int it = 0; it < T_BLK / 16; ++it) {            // 32 iterations
        const int tl = it * 16 + t_lo;
        const f4 v = s_tab[s_off[tl] + s4];
        __builtin_nontemporal_store(v, &out4[obase + it * (16 * 128)]);
    }
}

extern "C" void kernel_launch(void* const* d_in, const int* in_sizes, int n_in,
                              void* d_out, int out_size, void* d_ws, size_t ws_size,
                              hipStream_t stream) {
    const int*   input_ids  = (const int*)d_in[0];
    const int*   item_codes = (const int*)d_in[1];
    const float* centroids  = (const float*)d_in[2];
    float*       out        = (float*)d_out;

    dim3 grid(8 * (NTOK_ / T_BLK)), block(THREADS);   // 2048 blocks x 256
    ItemCode_kernel<<<grid, block, 0, stream>>>(input_ids, item_codes, centroids, out);
}

// Round 5
// 59.727 us; speedup vs baseline: 1.3720x; 1.3720x over previous
//
#include <hip/hip_runtime.h>

// ItemCode: PQ-coded embedding reconstruction.
//   input_ids : (256, 512) int32
//   item_codes: (1000000, 8) int32
//   centroids : (8, 256, 64) float32   (row 0 of each subspace is all-zero)
//   out       : (256, 512, 512) float32
//
// Round-2 structure (best so far): per-block token chunk, one barrier,
// fully-contiguous store stream (round-4 lesson: strided/fragmented stores
// are fatal; round-3 lesson: extra barriers drain the store queue).
// Round-5 changes: 32-token blocks x 4096 (2 residency rounds -> second
// round's gather hides under first round's stream), normal cached stores
// (full-line wave writes, L2 write-back aggregation) instead of NT.

#define VALS_ 256
#define NTOK_ (256 * 512)
#define TOKS_BLK 32
#define THREADS 256
#define ITERS (TOKS_BLK * 128 / THREADS)   // 16 float4-stores per thread

typedef float f4 __attribute__((ext_vector_type(4)));

__global__ __launch_bounds__(THREADS) void ItemCode_kernel(
    const int* __restrict__ input_ids,
    const int* __restrict__ item_codes,
    const float* __restrict__ centroids,
    float* __restrict__ out)
{
    __shared__ int s_off[TOKS_BLK * 8];     // 1 KB: centroid f4-row base per (tok, m)

    const int tid = threadIdx.x;
    const int tok0 = blockIdx.x * TOKS_BLK;

    // --- gather: exactly one dependent chain per thread (shortest exposure)
    {
        const int pt = tid >> 3;            // token within chunk
        const int pm = tid & 7;             // PQ sub-space
        const int id = input_ids[tok0 + pt];           // L2-resident, 8-way bcast
        int code = __builtin_nontemporal_load(&item_codes[id * 8 + pm]); // single-use line
        code = min(code, VALS_ - 1);
        code = id ? code : 0;               // pad -> row 0 (all-zero by construction)
        s_off[tid] = ((pm << 8) + code) << 4;
    }
    __syncthreads();                        // the ONLY barrier

    // --- stream: pure {LDS bcast read -> L2-hit centroid load -> cached store}
    const int e  = tid & 127;               // f4 slot within token
    const int m  = e >> 4;
    const int t0 = tid >> 7;                // 0 or 1
    const int s4 = e & 15;

    const f4* __restrict__ cent4 = reinterpret_cast<const f4*>(centroids);
    f4* __restrict__ out4 = reinterpret_cast<f4*>(out);
    const int ob = tok0 * 128;              // block writes 64 KB contiguous

    #pragma unroll
    for (int it = 0; it < ITERS; ++it) {
        const int t  = t0 + it * 2;
        const int ci = s_off[(t << 3) | m] + s4;       // 16-way LDS broadcast
        out4[ob + tid + it * THREADS] = cent4[ci];     // full-line wave store
    }
}

extern "C" void kernel_launch(void* const* d_in, const int* in_sizes, int n_in,
                              void* d_out, int out_size, void* d_ws, size_t ws_size,
                              hipStream_t stream) {
    const int*   input_ids  = (const int*)d_in[0];
    const int*   item_codes = (const int*)d_in[1];
    const float* centroids  = (const float*)d_in[2];
    float*       out        = (float*)d_out;

    dim3 grid(NTOK_ / TOKS_BLK), block(THREADS);   // 4096 blocks x 256
    ItemCode_kernel<<<grid, block, 0, stream>>>(input_ids, item_codes, centroids, out);
}

// Round 6
// 58.470 us; speedup vs baseline: 1.4015x; 1.0215x over previous
//
#include <hip/hip_runtime.h>

// ItemCode: PQ-coded embedding reconstruction.
//   input_ids : (256, 512) int32
//   item_codes: (1000000, 8) int32
//   centroids : (8, 256, 64) float32   (row 0 of each subspace is all-zero)
//   out       : (256, 512, 512) float32
//
// Lessons so far: contiguous store stream is king (r4), extra barriers drain
// the store queue (r3), NT-vs-cached stores is a wash (r5).
// Round-6 change: three-phase thread body -- (A) all LDS offset reads,
// (B) all 16 centroid loads into registers (max MLP, one wait),
// (C) 16 back-to-back stores with no interleaved waits. Removes any
// per-iteration lgkmcnt/vmcnt gating of store issue.

#define VALS_ 256
#define NTOK_ (256 * 512)
#define TOKS_BLK 32
#define THREADS 256
#define ITERS 16                  // float4-stores per thread

typedef float f4 __attribute__((ext_vector_type(4)));

__global__ __launch_bounds__(THREADS) void ItemCode_kernel(
    const int* __restrict__ input_ids,
    const int* __restrict__ item_codes,
    const float* __restrict__ centroids,
    float* __restrict__ out)
{
    __shared__ int s_off[TOKS_BLK * 8];     // 1 KB: centroid f4-row base per (tok, m)

    const int tid = threadIdx.x;
    const int tok0 = blockIdx.x * TOKS_BLK;

    // --- gather: one dependent chain per thread
    {
        const int pt = tid >> 3;            // token within chunk
        const int pm = tid & 7;             // PQ sub-space
        const int id = input_ids[tok0 + pt];
        int code = __builtin_nontemporal_load(&item_codes[id * 8 + pm]);
        code = min(code, VALS_ - 1);
        code = id ? code : 0;               // pad -> row 0 (all-zero by construction)
        s_off[tid] = ((pm << 8) + code) << 4;
    }
    __syncthreads();                        // the ONLY barrier

    const int e  = tid & 127;
    const int m  = e >> 4;
    const int t0 = tid >> 7;                // 0 or 1
    const int s4 = e & 15;

    const f4* __restrict__ cent4 = reinterpret_cast<const f4*>(centroids);
    f4* __restrict__ out4 = reinterpret_cast<f4*>(out);
    const int ob = tok0 * 128;

    // Phase A: all offset reads (lgkmcnt drains once, before any store)
    int ci[ITERS];
    #pragma unroll
    for (int it = 0; it < ITERS; ++it)
        ci[it] = s_off[((t0 + it * 2) << 3) | m] + s4;

    // Phase B: all centroid loads -> registers (16 VMEM ops in flight)
    f4 v[ITERS];
    #pragma unroll
    for (int it = 0; it < ITERS; ++it)
        v[it] = cent4[ci[it]];

    // Phase C: pure store burst, no interleaved waits
    #pragma unroll
    for (int it = 0; it < ITERS; ++it)
        __builtin_nontemporal_store(v[it], &out4[ob + tid + it * THREADS]);
}

extern "C" void kernel_launch(void* const* d_in, const int* in_sizes, int n_in,
                              void* d_out, int out_size, void* d_ws, size_t ws_size,
                              hipStream_t stream) {
    const int*   input_ids  = (const int*)d_in[0];
    const int*   item_codes = (const int*)d_in[1];
    const float* centroids  = (const float*)d_in[2];
    float*       out        = (float*)d_out;

    dim3 grid(NTOK_ / TOKS_BLK), block(THREADS);   // 4096 blocks x 256
    ItemCode_kernel<<<grid, block, 0, stream>>>(input_ids, item_codes, centroids, out);
}

// Round 7
// 58.187 us; speedup vs baseline: 1.4084x; 1.0049x over previous
//
#include <hip/hip_runtime.h>

// ItemCode: PQ-coded embedding reconstruction.
//   input_ids : (256, 512) int32
//   item_codes: (1000000, 8) int32
//   centroids : (8, 256, 64) float32   (row 0 of each subspace is all-zero)
//   out       : (256, 512, 512) float32
//
// Round-7: barrier-free / LDS-free. Each wave independently owns 8 tokens:
// lane l holds the centroid-row offset for (token l>>3, m l&7) in a register;
// the stream phase redistributes offsets via __shfl (no barrier, no LDS),
// then 16 loads -> 16 contiguous NT stores (16 KB linear per wave).
// Waves never synchronize: gather latency of one wave hides under the
// store streams of the others.
// Pad tokens (id==0) route to code 0, whose centroid row is all-zero.

#define VALS_ 256
#define NTOK_ (256 * 512)
#define TOKS_BLK 32               // 8 per wave
#define THREADS 256
#define ITERS 16                  // f4-stores per lane (8 tok * 128 f4 / 64 lanes)

typedef float f4 __attribute__((ext_vector_type(4)));

__global__ __launch_bounds__(THREADS) void ItemCode_kernel(
    const int* __restrict__ input_ids,
    const int* __restrict__ item_codes,
    const float* __restrict__ centroids,
    float* __restrict__ out)
{
    const int tid  = threadIdx.x;
    const int wave = tid >> 6;
    const int lane = tid & 63;

    const int tok0w = blockIdx.x * TOKS_BLK + wave * 8;   // this wave's 8 tokens

    // --- gather (per-wave, register-resident): lane l -> (token l>>3, m l&7)
    const int id = input_ids[tok0w + (lane >> 3)];        // 8-way broadcast load
    int code = __builtin_nontemporal_load(&item_codes[id * 8 + (lane & 7)]);
    code = min(code, VALS_ - 1);
    code = id ? code : 0;                 // pad -> row 0 (all-zero by construction)
    const int off = (((lane & 7) << 8) + code) << 4;      // f4 base of centroid row

    // --- stream: offsets via shfl, then phased loads, then contiguous stores
    const f4* __restrict__ cent4 = reinterpret_cast<const f4*>(centroids);
    f4* __restrict__ out4 = reinterpret_cast<f4*>(out);
    const int ob = tok0w * 128 + lane;    // wave writes 16 KB contiguous
    const int s4 = lane & 15;

    int ci[ITERS];
    #pragma unroll
    for (int it = 0; it < ITERS; ++it) {
        // flat f4 index within wave region: f = it*64 + lane
        // t_local = it>>1 ; m = (it&1)*4 + (lane>>4) ; owner = t_local*8 + m
        const int owner = ((it >> 1) << 3) | ((it & 1) << 2) | (lane >> 4);
        ci[it] = __shfl(off, owner) + s4;
    }

    f4 v[ITERS];
    #pragma unroll
    for (int it = 0; it < ITERS; ++it)
        v[it] = cent4[ci[it]];            // 16 independent VMEM loads in flight

    #pragma unroll
    for (int it = 0; it < ITERS; ++it)
        __builtin_nontemporal_store(v[it], &out4[ob + it * 64]);
}

extern "C" void kernel_launch(void* const* d_in, const int* in_sizes, int n_in,
                              void* d_out, int out_size, void* d_ws, size_t ws_size,
                              hipStream_t stream) {
    const int*   input_ids  = (const int*)d_in[0];
    const int*   item_codes = (const int*)d_in[1];
    const float* centroids  = (const float*)d_in[2];
    float*       out        = (float*)d_out;

    dim3 grid(NTOK_ / TOKS_BLK), block(THREADS);   // 4096 blocks x 256
    ItemCode_kernel<<<grid, block, 0, stream>>>(input_ids, item_codes, centroids, out);
}